// Round 6
// baseline (268.433 us; speedup 1.0000x reference)
//
#include <hip/hip_runtime.h>

#define F_IN  128
#define F_OUT 64

// ---------------------------------------------------------------------------
// GEMM: h[i] = x[i] @ W + b
// ---------------------------------------------------------------------------
__global__ __launch_bounds__(256) void gemm_h_kernel(
    const float* __restrict__ x, const float* __restrict__ W,
    const float* __restrict__ bias, float* __restrict__ h, int lo, int cnt) {
  __shared__ float sW[F_IN * F_OUT];   // 32 KB
  __shared__ float sx[16][132];

  const int t = threadIdx.x;
  const int base = blockIdx.x * 16;

  {
    const float4* W4 = (const float4*)W;
    float4* sW4 = (float4*)sW;
#pragma unroll
    for (int j = 0; j < 8; ++j) sW4[t + 256 * j] = W4[t + 256 * j];
  }
  {
#pragma unroll
    for (int j = 0; j < 2; ++j) {
      int idx = t + 256 * j;
      int r = idx >> 5;
      int c = idx & 31;
      int li = base + r;
      float4 v = make_float4(0.f, 0.f, 0.f, 0.f);
      if (li < cnt) v = ((const float4*)x)[(size_t)(lo + li) * 32 + c];
      *(float4*)&sx[r][c * 4] = v;
    }
  }
  __syncthreads();

  const int wave = t >> 6;
  const int lane = t & 63;
  const int nl = wave * 4 + (lane >> 4);
  const int f0 = (lane & 15) * 4;
  const int li = base + nl;

  float4 acc = *(const float4*)&bias[f0];

#pragma unroll
  for (int k = 0; k < F_IN; k += 4) {
    float4 xv = *(const float4*)&sx[nl][k];
#pragma unroll
    for (int j = 0; j < 4; ++j) {
      float4 wv = *(const float4*)&sW[(k + j) * F_OUT + f0];
      float xs = (j == 0) ? xv.x : (j == 1) ? xv.y : (j == 2) ? xv.z : xv.w;
      acc.x += xs * wv.x;
      acc.y += xs * wv.y;
      acc.z += xs * wv.z;
      acc.w += xs * wv.w;
    }
  }

  if (li < cnt) *(float4*)&h[(size_t)li * F_OUT + f0] = acc;
}

// ---------------------------------------------------------------------------
// CSR build: histogram -> scan -> two-level partition scatter
// ---------------------------------------------------------------------------
__global__ __launch_bounds__(256) void hist_kernel(
    const int* __restrict__ rows, int* __restrict__ cnt, int E) {
  int e = blockIdx.x * blockDim.x + threadIdx.x;
  if (e < E) atomicAdd(&cnt[rows[e]], 1);
}

__global__ __launch_bounds__(256) void scan1_kernel(
    const int* __restrict__ cnt, int* __restrict__ lscan,
    int* __restrict__ partials, int N) {
  __shared__ int s[256];
  const int b = blockIdx.x, t = threadIdx.x;
  const int base = b * 1024 + t * 4;
  int v0 = 0, v1 = 0, v2 = 0, v3 = 0;
  if (base + 3 < N) {
    int4 v = *(const int4*)&cnt[base];
    v0 = v.x; v1 = v.y; v2 = v.z; v3 = v.w;
  } else {
    if (base     < N) v0 = cnt[base];
    if (base + 1 < N) v1 = cnt[base + 1];
    if (base + 2 < N) v2 = cnt[base + 2];
    if (base + 3 < N) v3 = cnt[base + 3];
  }
  int tsum = v0 + v1 + v2 + v3;
  s[t] = tsum;
  __syncthreads();
  for (int off = 1; off < 256; off <<= 1) {
    int a = (t >= off) ? s[t - off] : 0;
    __syncthreads();
    s[t] += a;
    __syncthreads();
  }
  int excl = s[t] - tsum;
  if (base     < N) lscan[base]     = excl;
  if (base + 1 < N) lscan[base + 1] = excl + v0;
  if (base + 2 < N) lscan[base + 2] = excl + v0 + v1;
  if (base + 3 < N) lscan[base + 3] = excl + v0 + v1 + v2;
  if (t == 255) partials[b] = s[255];
}

__global__ __launch_bounds__(256) void scan2_kernel(int* __restrict__ p, int nb) {
  __shared__ int s[256];
  const int t = threadIdx.x;
  int v = (t < nb) ? p[t] : 0;
  s[t] = v;
  __syncthreads();
  for (int off = 1; off < 256; off <<= 1) {
    int a = (t >= off) ? s[t - off] : 0;
    __syncthreads();
    s[t] += a;
    __syncthreads();
  }
  if (t < nb) p[t] = s[t] - v;   // exclusive
}

// Finalize row_start, init per-row cursor, init per-bucket global cursors
// gcur[b] = row_start[b*rpx] (exact-fit bucket regions, same div everywhere).
__global__ __launch_bounds__(256) void scan3_kernel(
    int* __restrict__ row_start, const int* __restrict__ partials,
    int* __restrict__ cursor, int* __restrict__ gcur, int N, int E, int rpx) {
  int i = blockIdx.x * blockDim.x + threadIdx.x;
  if (i < N) {
    int v = row_start[i] + partials[i >> 10];
    row_start[i] = v;
    cursor[i] = v;
    if (i % rpx == 0) gcur[i / rpx] = v;
  }
  if (i == 0) row_start[N] = E;
}

// partA: single pass over edges; per-block LDS bucket counts -> one global
// reservation per (block,bucket) -> packed (local_row<<17 | col) writes into
// bucket-contiguous regions of tmp. Regions are exactly row_start-aligned.
#define PART_CHUNK 4096
__global__ __launch_bounds__(256) void part_a_kernel(
    const int* __restrict__ rows, const int* __restrict__ cols,
    int* __restrict__ gcur, unsigned int* __restrict__ tmp, int E, int rpx) {
  __shared__ int cnt8[8];
  __shared__ int cur8[8];
  const int t = threadIdx.x;
  int beg = blockIdx.x * PART_CHUNK;
  int end = beg + PART_CHUNK; if (end > E) end = E;

  if (t < 8) cnt8[t] = 0;
  __syncthreads();
  for (int e = beg + t; e < end; e += 256) {
    int b = rows[e] / rpx;
    atomicAdd(&cnt8[b], 1);
  }
  __syncthreads();
  if (t < 8) cur8[t] = atomicAdd(&gcur[t], cnt8[t]);
  __syncthreads();
  for (int e = beg + t; e < end; e += 256) {
    int r = rows[e];
    int b = r / rpx;
    int pos = atomicAdd(&cur8[b], 1);
    tmp[pos] = ((unsigned int)(r - b * rpx) << 17) | (unsigned int)cols[e];
  }
}

// partB: XCD-routed local reorder. Block b serves bucket (b&7): cursor slice
// (~50 KB) and dst window (~800 KB) stay in that XCD's L2.
__global__ __launch_bounds__(256) void part_b_kernel(
    const int* __restrict__ row_start, const unsigned int* __restrict__ tmp,
    int* __restrict__ cursor, int* __restrict__ dst, int N, int rpx) {
  const int b = blockIdx.x;
  const int xcd = b & 7;
  const int grp = b >> 3;
  const int ngrp = gridDim.x >> 3;
  const int lo_row = xcd * rpx;
  if (lo_row >= N) return;
  int hi_row = lo_row + rpx; if (hi_row > N) hi_row = N;
  const int start = row_start[lo_row];
  const int stop  = row_start[hi_row];
  const int cnt = stop - start;
  const int chunk = (cnt + ngrp - 1) / ngrp;
  int kbeg = start + grp * chunk;
  int kend = kbeg + chunk; if (kend > stop) kend = stop;
  for (int k = kbeg + threadIdx.x; k < kend; k += 256) {
    unsigned int p = tmp[k];
    int r = lo_row + (int)(p >> 17);
    int c = (int)(p & 0x1FFFFu);
    int pos = atomicAdd(&cursor[r], 1);
    dst[pos] = c;
  }
}

// ---------------------------------------------------------------------------
// Gather: one 64-lane wave per row; lane owns one feature. 8-wide MLP.
// ---------------------------------------------------------------------------
__global__ __launch_bounds__(256) void gather_kernel(
    const int* __restrict__ row_start, const int* __restrict__ dst,
    const float* __restrict__ h, float* __restrict__ out, int N) {
  int wid = (int)(((long long)blockIdx.x * blockDim.x + threadIdx.x) >> 6);
  int lane = threadIdx.x & 63;
  if (wid >= N) return;
  int beg = row_start[wid];
  int end = row_start[wid + 1];
  float a0 = 0.f, a1 = 0.f, a2 = 0.f, a3 = 0.f;
  int j = beg;
  for (; j + 7 < end; j += 8) {
    int c0 = dst[j],     c1 = dst[j + 1], c2 = dst[j + 2], c3 = dst[j + 3];
    int c4 = dst[j + 4], c5 = dst[j + 5], c6 = dst[j + 6], c7 = dst[j + 7];
    a0 += h[(size_t)c0 * F_OUT + lane];
    a1 += h[(size_t)c1 * F_OUT + lane];
    a2 += h[(size_t)c2 * F_OUT + lane];
    a3 += h[(size_t)c3 * F_OUT + lane];
    a0 += h[(size_t)c4 * F_OUT + lane];
    a1 += h[(size_t)c5 * F_OUT + lane];
    a2 += h[(size_t)c6 * F_OUT + lane];
    a3 += h[(size_t)c7 * F_OUT + lane];
  }
  for (; j + 3 < end; j += 4) {
    int c0 = dst[j], c1 = dst[j + 1], c2 = dst[j + 2], c3 = dst[j + 3];
    a0 += h[(size_t)c0 * F_OUT + lane];
    a1 += h[(size_t)c1 * F_OUT + lane];
    a2 += h[(size_t)c2 * F_OUT + lane];
    a3 += h[(size_t)c3 * F_OUT + lane];
  }
  for (; j < end; ++j) a0 += h[(size_t)dst[j] * F_OUT + lane];
  out[(size_t)wid * F_OUT + lane] = (a0 + a1) + (a2 + a3);
}

// ---------------------------------------------------------------------------
// Fallback kernels (small ws): chunked atomic path.
// ---------------------------------------------------------------------------
__global__ __launch_bounds__(256) void scatter_kernel(
    const int* __restrict__ rows, const int* __restrict__ cols,
    const float* __restrict__ h, float* __restrict__ out, int E, int lo, int hi) {
  long long tid = (long long)blockIdx.x * blockDim.x + threadIdx.x;
  int e = (int)(tid >> 4);
  int q = (int)(tid & 15);
  if (e >= E) return;
  int c = cols[e];
  if (c < lo || c >= hi) return;
  int r = rows[e];
  float4 v = ((const float4*)h)[(size_t)(c - lo) * 16 + q];
  float* o = out + (size_t)r * F_OUT + q * 4;
  atomicAdd(o + 0, v.x);
  atomicAdd(o + 1, v.y);
  atomicAdd(o + 2, v.z);
  atomicAdd(o + 3, v.w);
}

__global__ __launch_bounds__(256) void fused_kernel(
    const float* __restrict__ x, const float* __restrict__ W,
    const float* __restrict__ bias,
    const int* __restrict__ rows, const int* __restrict__ cols,
    float* __restrict__ out, int E) {
  long long tid = (long long)blockIdx.x * blockDim.x + threadIdx.x;
  int e = (int)(tid >> 6);
  int f = (int)(tid & 63);
  if (e >= E) return;
  int c = cols[e];
  int r = rows[e];
  const float* xr = x + (size_t)c * F_IN;
  float acc = bias[f];
#pragma unroll 8
  for (int k = 0; k < F_IN; ++k) acc += xr[k] * W[k * F_OUT + f];
  atomicAdd(&out[(size_t)r * F_OUT + f], acc);
}

extern "C" void kernel_launch(void* const* d_in, const int* in_sizes, int n_in,
                              void* d_out, int out_size, void* d_ws, size_t ws_size,
                              hipStream_t stream) {
  const float* x    = (const float*)d_in[0];
  const int*   rows = (const int*)d_in[1];        // edge_index row 0 (int32)
  const float* Ww   = (const float*)d_in[2];      // [128, 64]
  const float* Wb   = (const float*)d_in[3];      // [64]
  // d_in[4]/d_in[5] (a_w, a_b) are dead: softmax over a size-1 axis == 1.

  const int N = in_sizes[0] / F_IN;   // 100000
  const int E = in_sizes[1] / 2;      // 1600000
  const int* cols = rows + E;         // edge_index row 1

  float* out = (float*)d_out;
  char*  ws  = (char*)d_ws;

  // --- workspace layout; tmp aliases h (gemm runs AFTER partB frees tmp) ---
  size_t off = 0;
  auto alloc = [&](size_t bytes) {
    size_t o = off;
    off = (off + bytes + 255) & ~(size_t)255;
    return o;
  };
  const int nb = (N + 1023) / 1024;                 // scan blocks
  size_t hOff    = alloc((size_t)N * F_OUT * 4);    // 25.6 MB (tmp aliases)
  size_t cntOff  = alloc((size_t)N * 4);
  size_t rsOff   = alloc((size_t)(N + 1) * 4);
  size_t curOff  = alloc((size_t)N * 4);
  size_t dstOff  = alloc((size_t)E * 4);            // 6.4 MB
  size_t partOff = alloc((size_t)nb * 4);
  size_t gcurOff = alloc(8 * 4);

  const int rpx = (N + 7) / 8;                      // rows per bucket/XCD
  const bool csr_ok = (off <= ws_size) && (nb <= 256) &&
                      (N <= 131072) && ((size_t)E * 4 <= (size_t)N * F_OUT * 4);

  if (csr_ok) {
    float* h         = (float*)(ws + hOff);
    unsigned int* tmp = (unsigned int*)(ws + hOff);  // alias, freed before gemm
    int*   cnt       = (int*)(ws + cntOff);
    int*   row_start = (int*)(ws + rsOff);
    int*   cursor    = (int*)(ws + curOff);
    int*   dst       = (int*)(ws + dstOff);
    int*   partials  = (int*)(ws + partOff);
    int*   gcur      = (int*)(ws + gcurOff);

    hipMemsetAsync(cnt, 0, (size_t)N * 4, stream);
    hist_kernel<<<(E + 255) / 256, 256, 0, stream>>>(rows, cnt, E);
    scan1_kernel<<<nb, 256, 0, stream>>>(cnt, row_start, partials, N);
    scan2_kernel<<<1, 256, 0, stream>>>(partials, nb);
    scan3_kernel<<<(N + 255) / 256, 256, 0, stream>>>(row_start, partials,
                                                      cursor, gcur, N, E, rpx);
    part_a_kernel<<<(E + PART_CHUNK - 1) / PART_CHUNK, 256, 0, stream>>>(
        rows, cols, gcur, tmp, E, rpx);
    part_b_kernel<<<2048, 256, 0, stream>>>(row_start, tmp, cursor, dst, N, rpx);
    // tmp dead from here; gemm reuses the slot for h.
    gemm_h_kernel<<<(N + 15) / 16, 256, 0, stream>>>(x, Ww, Wb, h, 0, N);
    long long gthreads = (long long)N * 64;
    gather_kernel<<<(int)((gthreads + 255) / 256), 256, 0, stream>>>(
        row_start, dst, h, out, N);
    return;
  }

  // --- fallback: chunked atomic path (proven, ~1.4 ms) ---
  hipMemsetAsync(d_out, 0, (size_t)out_size * sizeof(float), stream);

  int chunkN = (int)((ws_size / (F_OUT * sizeof(float))) & ~(size_t)15);
  if (chunkN > N) chunkN = N;

  if (chunkN >= 16) {
    float* h = (float*)d_ws;
    int scatterBlocks = (int)(((long long)E * 16 + 255) / 256);
    for (int lo = 0; lo < N; lo += chunkN) {
      int cnt2 = (N - lo < chunkN) ? (N - lo) : chunkN;
      gemm_h_kernel<<<(cnt2 + 15) / 16, 256, 0, stream>>>(x, Ww, Wb, h, lo, cnt2);
      scatter_kernel<<<scatterBlocks, 256, 0, stream>>>(rows, cols, h, out, E,
                                                        lo, lo + cnt2);
    }
  } else {
    long long threads = (long long)E * 64;
    int blocks = (int)((threads + 255) / 256);
    fused_kernel<<<blocks, 256, 0, stream>>>(x, Ww, Wb, rows, cols, out, E);
  }
}

// Round 7
// 267.698 us; speedup vs baseline: 1.0027x; 1.0027x over previous
//
#include <hip/hip_runtime.h>

#define F_IN  128
#define F_OUT 64
#define NB    64   // level-1 buckets
#define NS    64   // level-2 sub-buckets per bucket

// ---------------------------------------------------------------------------
// GEMM: h[i] = x[i] @ W + b
// ---------------------------------------------------------------------------
__global__ __launch_bounds__(256) void gemm_h_kernel(
    const float* __restrict__ x, const float* __restrict__ W,
    const float* __restrict__ bias, float* __restrict__ h, int lo, int cnt) {
  __shared__ float sW[F_IN * F_OUT];   // 32 KB
  __shared__ float sx[16][132];

  const int t = threadIdx.x;
  const int base = blockIdx.x * 16;

  {
    const float4* W4 = (const float4*)W;
    float4* sW4 = (float4*)sW;
#pragma unroll
    for (int j = 0; j < 8; ++j) sW4[t + 256 * j] = W4[t + 256 * j];
  }
  {
#pragma unroll
    for (int j = 0; j < 2; ++j) {
      int idx = t + 256 * j;
      int r = idx >> 5;
      int c = idx & 31;
      int li = base + r;
      float4 v = make_float4(0.f, 0.f, 0.f, 0.f);
      if (li < cnt) v = ((const float4*)x)[(size_t)(lo + li) * 32 + c];
      *(float4*)&sx[r][c * 4] = v;
    }
  }
  __syncthreads();

  const int wave = t >> 6;
  const int lane = t & 63;
  const int nl = wave * 4 + (lane >> 4);
  const int f0 = (lane & 15) * 4;
  const int li = base + nl;

  float4 acc = *(const float4*)&bias[f0];

#pragma unroll
  for (int k = 0; k < F_IN; k += 4) {
    float4 xv = *(const float4*)&sx[nl][k];
#pragma unroll
    for (int j = 0; j < 4; ++j) {
      float4 wv = *(const float4*)&sW[(k + j) * F_OUT + f0];
      float xs = (j == 0) ? xv.x : (j == 1) ? xv.y : (j == 2) ? xv.z : xv.w;
      acc.x += xs * wv.x;
      acc.y += xs * wv.y;
      acc.z += xs * wv.z;
      acc.w += xs * wv.w;
    }
  }

  if (li < cnt) *(float4*)&h[(size_t)li * F_OUT + f0] = acc;
}

// ---------------------------------------------------------------------------
// CSR build: hist -> scan -> 3-level radix partition by row
// ---------------------------------------------------------------------------
__global__ __launch_bounds__(256) void hist_kernel(
    const int* __restrict__ rows, int* __restrict__ cnt, int E) {
  int e = blockIdx.x * blockDim.x + threadIdx.x;
  if (e < E) atomicAdd(&cnt[rows[e]], 1);
}

__global__ __launch_bounds__(256) void scan1_kernel(
    const int* __restrict__ cnt, int* __restrict__ lscan,
    int* __restrict__ partials, int N) {
  __shared__ int s[256];
  const int b = blockIdx.x, t = threadIdx.x;
  const int base = b * 1024 + t * 4;
  int v0 = 0, v1 = 0, v2 = 0, v3 = 0;
  if (base + 3 < N) {
    int4 v = *(const int4*)&cnt[base];
    v0 = v.x; v1 = v.y; v2 = v.z; v3 = v.w;
  } else {
    if (base     < N) v0 = cnt[base];
    if (base + 1 < N) v1 = cnt[base + 1];
    if (base + 2 < N) v2 = cnt[base + 2];
    if (base + 3 < N) v3 = cnt[base + 3];
  }
  int tsum = v0 + v1 + v2 + v3;
  s[t] = tsum;
  __syncthreads();
  for (int off = 1; off < 256; off <<= 1) {
    int a = (t >= off) ? s[t - off] : 0;
    __syncthreads();
    s[t] += a;
    __syncthreads();
  }
  int excl = s[t] - tsum;
  if (base     < N) lscan[base]     = excl;
  if (base + 1 < N) lscan[base + 1] = excl + v0;
  if (base + 2 < N) lscan[base + 2] = excl + v0 + v1;
  if (base + 3 < N) lscan[base + 3] = excl + v0 + v1 + v2;
  if (t == 255) partials[b] = s[255];
}

__global__ __launch_bounds__(256) void scan2_kernel(int* __restrict__ p, int nb) {
  __shared__ int s[256];
  const int t = threadIdx.x;
  int v = (t < nb) ? p[t] : 0;
  s[t] = v;
  __syncthreads();
  for (int off = 1; off < 256; off <<= 1) {
    int a = (t >= off) ? s[t - off] : 0;
    __syncthreads();
    s[t] += a;
    __syncthreads();
  }
  if (t < nb) p[t] = s[t] - v;   // exclusive
}

__global__ __launch_bounds__(256) void scan3_kernel(
    int* __restrict__ row_start, const int* __restrict__ partials,
    int* __restrict__ cursor, int N, int E) {
  int i = blockIdx.x * blockDim.x + threadIdx.x;
  if (i < N) {
    int v = row_start[i] + partials[i >> 10];
    row_start[i] = v;
    cursor[i] = v;
  }
  if (i == 0) row_start[N] = E;
}

// Init exact-fit bucket/sub-bucket cursors from finalized row_start.
__global__ __launch_bounds__(256) void init_gcur_kernel(
    const int* __restrict__ row_start, int* __restrict__ gcur1,
    int* __restrict__ gcur2, int N, int rpb, int rps) {
  int i = blockIdx.x * blockDim.x + threadIdx.x;
  if (i < NB) {
    int idx = i * rpb; if (idx > N) idx = N;
    gcur1[i] = row_start[idx];
  }
  if (i < NB * NS) {
    int b = i >> 6, s = i & (NS - 1);
    int loc = s * rps; if (loc > rpb) loc = rpb;
    int idx = b * rpb + loc; if (idx > N) idx = N;
    gcur2[i] = row_start[idx];
  }
}

// pass1: bucket edges by row/rpb into NB exact-fit regions of tmp.
// Per-(block,bucket) reservation -> contiguous multi-line write runs.
#define P1_CHUNK 4096
__global__ __launch_bounds__(256) void pass1_kernel(
    const int* __restrict__ rows, const int* __restrict__ cols,
    int* __restrict__ gcur1, unsigned int* __restrict__ tmp, int E, int rpb) {
  __shared__ int cnt64[NB];
  __shared__ int cur64[NB];
  const int t = threadIdx.x;
  int beg = blockIdx.x * P1_CHUNK;
  int end = beg + P1_CHUNK; if (end > E) end = E;

  if (t < NB) cnt64[t] = 0;
  __syncthreads();
  for (int e = beg + t; e < end; e += 256)
    atomicAdd(&cnt64[(unsigned)rows[e] / (unsigned)rpb], 1);
  __syncthreads();
  if (t < NB) cur64[t] = atomicAdd(&gcur1[t], cnt64[t]);
  __syncthreads();
  for (int e = beg + t; e < end; e += 256) {
    int r = rows[e];
    int b = (unsigned)r / (unsigned)rpb;
    int pos = atomicAdd(&cur64[b], 1);
    tmp[pos] = ((unsigned int)(r - b * rpb) << 17) | (unsigned int)cols[e];
  }
}

// pass2: within each bucket, re-bucket by local_row/rps into NS exact-fit
// sub-regions of tmp2. Same reservation trick -> coalesced write runs.
#define P2_BPB 8
__global__ __launch_bounds__(256) void pass2_kernel(
    const int* __restrict__ row_start, const unsigned int* __restrict__ tmp,
    int* __restrict__ gcur2, unsigned int* __restrict__ tmp2,
    int N, int rpb, int rps) {
  __shared__ int cnt64[NS];
  __shared__ int cur64[NS];
  const int b = blockIdx.x / P2_BPB;
  const int g = blockIdx.x % P2_BPB;
  const int t = threadIdx.x;
  int lo_row = b * rpb;
  if (lo_row >= N) return;
  int hi_row = lo_row + rpb; if (hi_row > N) hi_row = N;
  const int start = row_start[lo_row];
  const int stop  = row_start[hi_row];
  const int cnt = stop - start;
  const int chunk = (cnt + P2_BPB - 1) / P2_BPB;
  int kbeg = start + g * chunk;
  int kend = kbeg + chunk; if (kend > stop) kend = stop;

  if (t < NS) cnt64[t] = 0;
  __syncthreads();
  for (int k = kbeg + t; k < kend; k += 256)
    atomicAdd(&cnt64[(tmp[k] >> 17) / (unsigned)rps], 1);
  __syncthreads();
  if (t < NS) cur64[t] = atomicAdd(&gcur2[b * NS + t], cnt64[t]);
  __syncthreads();
  for (int k = kbeg + t; k < kend; k += 256) {
    unsigned int p = tmp[k];
    int s = (p >> 17) / (unsigned)rps;
    int pos = atomicAdd(&cur64[s], 1);
    tmp2[pos] = p;
  }
}

// pass3: final per-row cursor scatter. Sub-bucket regions are ~25 rows
// (~1.6 KB dst windows) so every dst line is filled by one block.
#define P3_BPB 32
__global__ __launch_bounds__(256) void pass3_kernel(
    const int* __restrict__ row_start, const unsigned int* __restrict__ tmp2,
    int* __restrict__ cursor, int* __restrict__ dst, int N, int rpb) {
  const int b = blockIdx.x / P3_BPB;
  const int g = blockIdx.x % P3_BPB;
  int lo_row = b * rpb;
  if (lo_row >= N) return;
  int hi_row = lo_row + rpb; if (hi_row > N) hi_row = N;
  const int start = row_start[lo_row];
  const int stop  = row_start[hi_row];
  const int cnt = stop - start;
  const int chunk = (cnt + P3_BPB - 1) / P3_BPB;
  int kbeg = start + g * chunk;
  int kend = kbeg + chunk; if (kend > stop) kend = stop;
  for (int k = kbeg + threadIdx.x; k < kend; k += 256) {
    unsigned int p = tmp2[k];
    int r = lo_row + (int)(p >> 17);
    int pos = atomicAdd(&cursor[r], 1);
    dst[pos] = (int)(p & 0x1FFFFu);
  }
}

// ---------------------------------------------------------------------------
// Gather: one 64-lane wave per row; lane owns one feature. 8-wide MLP.
// ---------------------------------------------------------------------------
__global__ __launch_bounds__(256) void gather_kernel(
    const int* __restrict__ row_start, const int* __restrict__ dst,
    const float* __restrict__ h, float* __restrict__ out, int N) {
  int wid = (int)(((long long)blockIdx.x * blockDim.x + threadIdx.x) >> 6);
  int lane = threadIdx.x & 63;
  if (wid >= N) return;
  int beg = row_start[wid];
  int end = row_start[wid + 1];
  float a0 = 0.f, a1 = 0.f, a2 = 0.f, a3 = 0.f;
  int j = beg;
  for (; j + 7 < end; j += 8) {
    int c0 = dst[j],     c1 = dst[j + 1], c2 = dst[j + 2], c3 = dst[j + 3];
    int c4 = dst[j + 4], c5 = dst[j + 5], c6 = dst[j + 6], c7 = dst[j + 7];
    a0 += h[(size_t)c0 * F_OUT + lane];
    a1 += h[(size_t)c1 * F_OUT + lane];
    a2 += h[(size_t)c2 * F_OUT + lane];
    a3 += h[(size_t)c3 * F_OUT + lane];
    a0 += h[(size_t)c4 * F_OUT + lane];
    a1 += h[(size_t)c5 * F_OUT + lane];
    a2 += h[(size_t)c6 * F_OUT + lane];
    a3 += h[(size_t)c7 * F_OUT + lane];
  }
  for (; j + 3 < end; j += 4) {
    int c0 = dst[j], c1 = dst[j + 1], c2 = dst[j + 2], c3 = dst[j + 3];
    a0 += h[(size_t)c0 * F_OUT + lane];
    a1 += h[(size_t)c1 * F_OUT + lane];
    a2 += h[(size_t)c2 * F_OUT + lane];
    a3 += h[(size_t)c3 * F_OUT + lane];
  }
  for (; j < end; ++j) a0 += h[(size_t)dst[j] * F_OUT + lane];
  out[(size_t)wid * F_OUT + lane] = (a0 + a1) + (a2 + a3);
}

// ---------------------------------------------------------------------------
// Fallback kernels (small ws): chunked atomic path.
// ---------------------------------------------------------------------------
__global__ __launch_bounds__(256) void scatter_kernel(
    const int* __restrict__ rows, const int* __restrict__ cols,
    const float* __restrict__ h, float* __restrict__ out, int E, int lo, int hi) {
  long long tid = (long long)blockIdx.x * blockDim.x + threadIdx.x;
  int e = (int)(tid >> 4);
  int q = (int)(tid & 15);
  if (e >= E) return;
  int c = cols[e];
  if (c < lo || c >= hi) return;
  int r = rows[e];
  float4 v = ((const float4*)h)[(size_t)(c - lo) * 16 + q];
  float* o = out + (size_t)r * F_OUT + q * 4;
  atomicAdd(o + 0, v.x);
  atomicAdd(o + 1, v.y);
  atomicAdd(o + 2, v.z);
  atomicAdd(o + 3, v.w);
}

__global__ __launch_bounds__(256) void fused_kernel(
    const float* __restrict__ x, const float* __restrict__ W,
    const float* __restrict__ bias,
    const int* __restrict__ rows, const int* __restrict__ cols,
    float* __restrict__ out, int E) {
  long long tid = (long long)blockIdx.x * blockDim.x + threadIdx.x;
  int e = (int)(tid >> 6);
  int f = (int)(tid & 63);
  if (e >= E) return;
  int c = cols[e];
  int r = rows[e];
  const float* xr = x + (size_t)c * F_IN;
  float acc = bias[f];
#pragma unroll 8
  for (int k = 0; k < F_IN; ++k) acc += xr[k] * W[k * F_OUT + f];
  atomicAdd(&out[(size_t)r * F_OUT + f], acc);
}

extern "C" void kernel_launch(void* const* d_in, const int* in_sizes, int n_in,
                              void* d_out, int out_size, void* d_ws, size_t ws_size,
                              hipStream_t stream) {
  const float* x    = (const float*)d_in[0];
  const int*   rows = (const int*)d_in[1];        // edge_index row 0 (int32)
  const float* Ww   = (const float*)d_in[2];      // [128, 64]
  const float* Wb   = (const float*)d_in[3];      // [64]
  // d_in[4]/d_in[5] (a_w, a_b) are dead: softmax over a size-1 axis == 1.

  const int N = in_sizes[0] / F_IN;   // 100000
  const int E = in_sizes[1] / 2;      // 1600000
  const int* cols = rows + E;         // edge_index row 1

  float* out = (float*)d_out;
  char*  ws  = (char*)d_ws;

  // --- workspace layout; tmp & tmp2 alias the h slot (dead before gemm) ---
  size_t off = 0;
  auto alloc = [&](size_t bytes) {
    size_t o = off;
    off = (off + bytes + 255) & ~(size_t)255;
    return o;
  };
  const int nb = (N + 1023) / 1024;                 // scan blocks
  const size_t eBytes = ((size_t)E * 4 + 255) & ~(size_t)255;
  size_t hOff    = alloc((size_t)N * F_OUT * 4);    // 25.6 MB (tmp/tmp2 alias)
  size_t cntOff  = alloc((size_t)N * 4);
  size_t rsOff   = alloc((size_t)(N + 1) * 4);
  size_t curOff  = alloc((size_t)N * 4);
  size_t dstOff  = alloc((size_t)E * 4);            // 6.4 MB
  size_t partOff = alloc((size_t)nb * 4);
  size_t g1Off   = alloc(NB * 4);
  size_t g2Off   = alloc(NB * NS * 4);

  const int rpb = (N + NB - 1) / NB;                // rows per bucket
  const int rps = (rpb + NS - 1) / NS;              // rows per sub-bucket
  const bool csr_ok = (off <= ws_size) && (nb <= 256) &&
                      (N <= 131072) &&               // 17-bit col, 15-bit local
                      (2 * eBytes <= (size_t)N * F_OUT * 4);

  if (csr_ok) {
    float*        h    = (float*)(ws + hOff);
    unsigned int* tmp  = (unsigned int*)(ws + hOff);
    unsigned int* tmp2 = (unsigned int*)(ws + hOff + eBytes);
    int* cnt       = (int*)(ws + cntOff);
    int* row_start = (int*)(ws + rsOff);
    int* cursor    = (int*)(ws + curOff);
    int* dst       = (int*)(ws + dstOff);
    int* partials  = (int*)(ws + partOff);
    int* gcur1     = (int*)(ws + g1Off);
    int* gcur2     = (int*)(ws + g2Off);

    hipMemsetAsync(cnt, 0, (size_t)N * 4, stream);
    hist_kernel<<<(E + 255) / 256, 256, 0, stream>>>(rows, cnt, E);
    scan1_kernel<<<nb, 256, 0, stream>>>(cnt, row_start, partials, N);
    scan2_kernel<<<1, 256, 0, stream>>>(partials, nb);
    scan3_kernel<<<(N + 255) / 256, 256, 0, stream>>>(row_start, partials,
                                                      cursor, N, E);
    init_gcur_kernel<<<(NB * NS + 255) / 256, 256, 0, stream>>>(
        row_start, gcur1, gcur2, N, rpb, rps);
    pass1_kernel<<<(E + P1_CHUNK - 1) / P1_CHUNK, 256, 0, stream>>>(
        rows, cols, gcur1, tmp, E, rpb);
    pass2_kernel<<<NB * P2_BPB, 256, 0, stream>>>(row_start, tmp, gcur2, tmp2,
                                                  N, rpb, rps);
    pass3_kernel<<<NB * P3_BPB, 256, 0, stream>>>(row_start, tmp2, cursor, dst,
                                                  N, rpb);
    // tmp/tmp2 dead from here; gemm reuses the slot for h.
    gemm_h_kernel<<<(N + 15) / 16, 256, 0, stream>>>(x, Ww, Wb, h, 0, N);
    long long gthreads = (long long)N * 64;
    gather_kernel<<<(int)((gthreads + 255) / 256), 256, 0, stream>>>(
        row_start, dst, h, out, N);
    return;
  }

  // --- fallback: chunked atomic path (proven, ~1.4 ms) ---
  hipMemsetAsync(d_out, 0, (size_t)out_size * sizeof(float), stream);

  int chunkN = (int)((ws_size / (F_OUT * sizeof(float))) & ~(size_t)15);
  if (chunkN > N) chunkN = N;

  if (chunkN >= 16) {
    float* h = (float*)d_ws;
    int scatterBlocks = (int)(((long long)E * 16 + 255) / 256);
    for (int lo = 0; lo < N; lo += chunkN) {
      int cnt2 = (N - lo < chunkN) ? (N - lo) : chunkN;
      gemm_h_kernel<<<(cnt2 + 15) / 16, 256, 0, stream>>>(x, Ww, Wb, h, lo, cnt2);
      scatter_kernel<<<scatterBlocks, 256, 0, stream>>>(rows, cols, h, out, E,
                                                        lo, lo + cnt2);
    }
  } else {
    long long threads = (long long)E * 64;
    int blocks = (int)((threads + 255) / 256);
    fused_kernel<<<blocks, 256, 0, stream>>>(x, Ww, Wb, rows, cols, out, E);
  }
}

// Round 8
// 175.734 us; speedup vs baseline: 1.5275x; 1.5233x over previous
//
#include <hip/hip_runtime.h>

#define F_IN  128
#define F_OUT 64
#define NB    64     // level-1 buckets
#define NS    64     // level-2 sub-buckets per bucket
#define NBIN  (NB * NS)
#define CNT_BLOCKS 128

// ---------------------------------------------------------------------------
// GEMM: h[i] = x[i] @ W + b
// ---------------------------------------------------------------------------
__global__ __launch_bounds__(256) void gemm_h_kernel(
    const float* __restrict__ x, const float* __restrict__ W,
    const float* __restrict__ bias, float* __restrict__ h, int lo, int cnt) {
  __shared__ float sW[F_IN * F_OUT];   // 32 KB
  __shared__ float sx[16][132];

  const int t = threadIdx.x;
  const int base = blockIdx.x * 16;

  {
    const float4* W4 = (const float4*)W;
    float4* sW4 = (float4*)sW;
#pragma unroll
    for (int j = 0; j < 8; ++j) sW4[t + 256 * j] = W4[t + 256 * j];
  }
  {
#pragma unroll
    for (int j = 0; j < 2; ++j) {
      int idx = t + 256 * j;
      int r = idx >> 5;
      int c = idx & 31;
      int li = base + r;
      float4 v = make_float4(0.f, 0.f, 0.f, 0.f);
      if (li < cnt) v = ((const float4*)x)[(size_t)(lo + li) * 32 + c];
      *(float4*)&sx[r][c * 4] = v;
    }
  }
  __syncthreads();

  const int wave = t >> 6;
  const int lane = t & 63;
  const int nl = wave * 4 + (lane >> 4);
  const int f0 = (lane & 15) * 4;
  const int li = base + nl;

  float4 acc = *(const float4*)&bias[f0];

#pragma unroll
  for (int k = 0; k < F_IN; k += 4) {
    float4 xv = *(const float4*)&sx[nl][k];
#pragma unroll
    for (int j = 0; j < 4; ++j) {
      float4 wv = *(const float4*)&sW[(k + j) * F_OUT + f0];
      float xs = (j == 0) ? xv.x : (j == 1) ? xv.y : (j == 2) ? xv.z : xv.w;
      acc.x += xs * wv.x;
      acc.y += xs * wv.y;
      acc.z += xs * wv.z;
      acc.w += xs * wv.w;
    }
  }

  if (li < cnt) *(float4*)&h[(size_t)li * F_OUT + f0] = acc;
}

// ---------------------------------------------------------------------------
// count: 4096-bin LDS histogram of rows; non-atomic per-block partials.
// bin(r) = (r/rpb)*NS + (r%rpb)/rps  -- must match pass1/pass2/pass3.
// ---------------------------------------------------------------------------
__global__ __launch_bounds__(256) void count_kernel(
    const int* __restrict__ rows, int* __restrict__ partial,
    int E, int rpb, int rps) {
  __shared__ int hist[NBIN];   // 16 KB
  const int t = threadIdx.x;
  for (int i = t; i < NBIN; i += 256) hist[i] = 0;
  __syncthreads();
  const int chunk = (E + gridDim.x - 1) / gridDim.x;
  int beg = blockIdx.x * chunk;
  int end = beg + chunk; if (end > E) end = E;
  for (int e = beg + t; e < end; e += 256) {
    int r = rows[e];
    int b = (unsigned)r / (unsigned)rpb;
    int s = (unsigned)(r - b * rpb) / (unsigned)rps;
    atomicAdd(&hist[(b << 6) + s], 1);
  }
  __syncthreads();
  int* dstp = partial + (size_t)blockIdx.x * NBIN;
  for (int i = t; i < NBIN; i += 256) dstp[i] = hist[i];
}

// reduce: bincnt[i] = sum over blocks of partial[k][i]
__global__ __launch_bounds__(256) void reduce_kernel(
    const int* __restrict__ partial, int* __restrict__ bincnt) {
  int i = blockIdx.x * blockDim.x + threadIdx.x;   // 4096 threads
  int s = 0;
  for (int k = 0; k < CNT_BLOCKS; ++k) s += partial[(size_t)k * NBIN + i];
  bincnt[i] = s;
}

// scan: single-block exclusive scan of 4096 bins -> bin_start[4097],
// gcur1[64] (bucket bases), gcur2[4096] (sub bases); row_start[N] = E.
__global__ __launch_bounds__(256) void scan_kernel(
    const int* __restrict__ bincnt, int* __restrict__ bin_start,
    int* __restrict__ gcur1, int* __restrict__ gcur2,
    int* __restrict__ row_start, int N, int E) {
  __shared__ int s[256];
  const int t = threadIdx.x;
  int v[16];
  int sum = 0;
#pragma unroll
  for (int j = 0; j < 16; ++j) { v[j] = bincnt[t * 16 + j]; sum += v[j]; }
  s[t] = sum;
  __syncthreads();
  for (int off = 1; off < 256; off <<= 1) {
    int a = (t >= off) ? s[t - off] : 0;
    __syncthreads();
    s[t] += a;
    __syncthreads();
  }
  int run = s[t] - sum;   // exclusive
#pragma unroll
  for (int j = 0; j < 16; ++j) {
    bin_start[t * 16 + j] = run;
    gcur2[t * 16 + j] = run;
    run += v[j];
  }
  if (t == 0) { bin_start[NBIN] = E; row_start[N] = E; }
  __syncthreads();
  if (t < NB) gcur1[t] = bin_start[t << 6];
}

// pass1: bucket edges by row/rpb into NB exact-fit regions of tmp.
#define P1_CHUNK 4096
__global__ __launch_bounds__(256) void pass1_kernel(
    const int* __restrict__ rows, const int* __restrict__ cols,
    int* __restrict__ gcur1, unsigned int* __restrict__ tmp, int E, int rpb) {
  __shared__ int cnt64[NB];
  __shared__ int cur64[NB];
  const int t = threadIdx.x;
  int beg = blockIdx.x * P1_CHUNK;
  int end = beg + P1_CHUNK; if (end > E) end = E;

  if (t < NB) cnt64[t] = 0;
  __syncthreads();
  for (int e = beg + t; e < end; e += 256)
    atomicAdd(&cnt64[(unsigned)rows[e] / (unsigned)rpb], 1);
  __syncthreads();
  if (t < NB) cur64[t] = atomicAdd(&gcur1[t], cnt64[t]);
  __syncthreads();
  for (int e = beg + t; e < end; e += 256) {
    int r = rows[e];
    int b = (unsigned)r / (unsigned)rpb;
    int pos = atomicAdd(&cur64[b], 1);
    tmp[pos] = ((unsigned int)(r - b * rpb) << 17) | (unsigned int)cols[e];
  }
}

// pass2: within each bucket, re-bucket by local_row/rps into exact-fit
// sub-regions of tmp2.
#define P2_BPB 8
__global__ __launch_bounds__(256) void pass2_kernel(
    const int* __restrict__ bin_start, const unsigned int* __restrict__ tmp,
    int* __restrict__ gcur2, unsigned int* __restrict__ tmp2, int rps) {
  __shared__ int cnt64[NS];
  __shared__ int cur64[NS];
  const int b = blockIdx.x / P2_BPB;
  const int g = blockIdx.x % P2_BPB;
  const int t = threadIdx.x;
  const int start = bin_start[b << 6];
  const int stop  = bin_start[(b + 1) << 6];
  const int cnt = stop - start;
  const int chunk = (cnt + P2_BPB - 1) / P2_BPB;
  int kbeg = start + g * chunk;
  int kend = kbeg + chunk; if (kend > stop) kend = stop;

  if (t < NS) cnt64[t] = 0;
  __syncthreads();
  for (int k = kbeg + t; k < kend; k += 256)
    atomicAdd(&cnt64[(tmp[k] >> 17) / (unsigned)rps], 1);
  __syncthreads();
  if (t < NS) cur64[t] = atomicAdd(&gcur2[(b << 6) + t], cnt64[t]);
  __syncthreads();
  for (int k = kbeg + t; k < kend; k += 256) {
    unsigned int p = tmp[k];
    int s = (p >> 17) / (unsigned)rps;
    int pos = atomicAdd(&cur64[s], 1);
    tmp2[pos] = p;
  }
}

// pass3: per sub-bucket (one block): LDS per-row count -> local scan ->
// write row_start for its <=rps rows -> LDS-cursor scatter into its
// ~few-KB dst window. Zero global atomics.
__global__ __launch_bounds__(256) void pass3_kernel(
    const int* __restrict__ bin_start, const unsigned int* __restrict__ tmp2,
    int* __restrict__ row_start, int* __restrict__ dst,
    int N, int rpb, int rps) {
  const int i = blockIdx.x;            // bin id
  const int b = i >> 6, s = i & (NS - 1);
  const int gr0 = b * rpb + s * rps;   // first global row of this bin
  if (gr0 >= N) return;
  int bucket_end = (b + 1) * rpb; if (bucket_end > N) bucket_end = N;
  int nrows = bucket_end - gr0; if (nrows > rps) nrows = rps;
  if (nrows <= 0) return;

  const int seg_lo = bin_start[i];
  const int seg_hi = bin_start[i + 1];
  const int lbase = s * rps;

  __shared__ int cnt[64];
  __shared__ int cur[64];
  const int t = threadIdx.x;
  if (t < 64) cnt[t] = 0;
  __syncthreads();
  for (int k = seg_lo + t; k < seg_hi; k += 256)
    atomicAdd(&cnt[(int)(tmp2[k] >> 17) - lbase], 1);
  __syncthreads();
  if (t == 0) {
    int run = 0;
    for (int j = 0; j < nrows; ++j) {
      int c = cnt[j];
      cur[j] = run;
      row_start[gr0 + j] = seg_lo + run;
      run += c;
    }
  }
  __syncthreads();
  for (int k = seg_lo + t; k < seg_hi; k += 256) {
    unsigned int p = tmp2[k];
    int lr = (int)(p >> 17) - lbase;
    int pos = seg_lo + atomicAdd(&cur[lr], 1);
    dst[pos] = (int)(p & 0x1FFFFu);
  }
}

// ---------------------------------------------------------------------------
// Gather: one 64-lane wave per row; lane owns one feature. 8-wide MLP.
// ---------------------------------------------------------------------------
__global__ __launch_bounds__(256) void gather_kernel(
    const int* __restrict__ row_start, const int* __restrict__ dst,
    const float* __restrict__ h, float* __restrict__ out, int N) {
  int wid = (int)(((long long)blockIdx.x * blockDim.x + threadIdx.x) >> 6);
  int lane = threadIdx.x & 63;
  if (wid >= N) return;
  int beg = row_start[wid];
  int end = row_start[wid + 1];
  float a0 = 0.f, a1 = 0.f, a2 = 0.f, a3 = 0.f;
  int j = beg;
  for (; j + 7 < end; j += 8) {
    int c0 = dst[j],     c1 = dst[j + 1], c2 = dst[j + 2], c3 = dst[j + 3];
    int c4 = dst[j + 4], c5 = dst[j + 5], c6 = dst[j + 6], c7 = dst[j + 7];
    a0 += h[(size_t)c0 * F_OUT + lane];
    a1 += h[(size_t)c1 * F_OUT + lane];
    a2 += h[(size_t)c2 * F_OUT + lane];
    a3 += h[(size_t)c3 * F_OUT + lane];
    a0 += h[(size_t)c4 * F_OUT + lane];
    a1 += h[(size_t)c5 * F_OUT + lane];
    a2 += h[(size_t)c6 * F_OUT + lane];
    a3 += h[(size_t)c7 * F_OUT + lane];
  }
  for (; j + 3 < end; j += 4) {
    int c0 = dst[j], c1 = dst[j + 1], c2 = dst[j + 2], c3 = dst[j + 3];
    a0 += h[(size_t)c0 * F_OUT + lane];
    a1 += h[(size_t)c1 * F_OUT + lane];
    a2 += h[(size_t)c2 * F_OUT + lane];
    a3 += h[(size_t)c3 * F_OUT + lane];
  }
  for (; j < end; ++j) a0 += h[(size_t)dst[j] * F_OUT + lane];
  out[(size_t)wid * F_OUT + lane] = (a0 + a1) + (a2 + a3);
}

// ---------------------------------------------------------------------------
// Fallback kernels (small ws): chunked atomic path.
// ---------------------------------------------------------------------------
__global__ __launch_bounds__(256) void scatter_kernel(
    const int* __restrict__ rows, const int* __restrict__ cols,
    const float* __restrict__ h, float* __restrict__ out, int E, int lo, int hi) {
  long long tid = (long long)blockIdx.x * blockDim.x + threadIdx.x;
  int e = (int)(tid >> 4);
  int q = (int)(tid & 15);
  if (e >= E) return;
  int c = cols[e];
  if (c < lo || c >= hi) return;
  int r = rows[e];
  float4 v = ((const float4*)h)[(size_t)(c - lo) * 16 + q];
  float* o = out + (size_t)r * F_OUT + q * 4;
  atomicAdd(o + 0, v.x);
  atomicAdd(o + 1, v.y);
  atomicAdd(o + 2, v.z);
  atomicAdd(o + 3, v.w);
}

__global__ __launch_bounds__(256) void fused_kernel(
    const float* __restrict__ x, const float* __restrict__ W,
    const float* __restrict__ bias,
    const int* __restrict__ rows, const int* __restrict__ cols,
    float* __restrict__ out, int E) {
  long long tid = (long long)blockIdx.x * blockDim.x + threadIdx.x;
  int e = (int)(tid >> 6);
  int f = (int)(tid & 63);
  if (e >= E) return;
  int c = cols[e];
  int r = rows[e];
  const float* xr = x + (size_t)c * F_IN;
  float acc = bias[f];
#pragma unroll 8
  for (int k = 0; k < F_IN; ++k) acc += xr[k] * W[k * F_OUT + f];
  atomicAdd(&out[(size_t)r * F_OUT + f], acc);
}

extern "C" void kernel_launch(void* const* d_in, const int* in_sizes, int n_in,
                              void* d_out, int out_size, void* d_ws, size_t ws_size,
                              hipStream_t stream) {
  const float* x    = (const float*)d_in[0];
  const int*   rows = (const int*)d_in[1];        // edge_index row 0 (int32)
  const float* Ww   = (const float*)d_in[2];      // [128, 64]
  const float* Wb   = (const float*)d_in[3];      // [64]
  // d_in[4]/d_in[5] (a_w, a_b) are dead: softmax over a size-1 axis == 1.

  const int N = in_sizes[0] / F_IN;   // 100000
  const int E = in_sizes[1] / 2;      // 1600000
  const int* cols = rows + E;         // edge_index row 1

  float* out = (float*)d_out;
  char*  ws  = (char*)d_ws;

  // --- workspace layout; tmp/tmp2/partial alias the h slot (dead pre-gemm) ---
  size_t off = 0;
  auto alloc = [&](size_t bytes) {
    size_t o = off;
    off = (off + bytes + 255) & ~(size_t)255;
    return o;
  };
  const size_t eBytes  = ((size_t)E * 4 + 255) & ~(size_t)255;
  const size_t hBytes  = (size_t)N * F_OUT * 4;
  const size_t pBytes  = (size_t)CNT_BLOCKS * NBIN * 4;   // 2 MB
  size_t hOff    = alloc(hBytes);                   // 25.6 MB
  size_t rsOff   = alloc((size_t)(N + 1) * 4);
  size_t dstOff  = alloc((size_t)E * 4);            // 6.4 MB
  size_t bcOff   = alloc(NBIN * 4);
  size_t bsOff   = alloc((NBIN + 1) * 4);
  size_t g1Off   = alloc(NB * 4);
  size_t g2Off   = alloc(NBIN * 4);

  const int rpb = (N + NB - 1) / NB;                // rows per bucket
  const int rps = (rpb + NS - 1) / NS;              // rows per sub-bucket
  const bool csr_ok = (off <= ws_size) &&
                      (N <= 131072) &&              // 17-bit col, 11-bit local
                      (2 * eBytes + pBytes <= hBytes);

  if (csr_ok) {
    float*        h       = (float*)(ws + hOff);
    unsigned int* tmp     = (unsigned int*)(ws + hOff);
    unsigned int* tmp2    = (unsigned int*)(ws + hOff + eBytes);
    int*          partial = (int*)(ws + hOff + 2 * eBytes);
    int* row_start = (int*)(ws + rsOff);
    int* dst       = (int*)(ws + dstOff);
    int* bincnt    = (int*)(ws + bcOff);
    int* bin_start = (int*)(ws + bsOff);
    int* gcur1     = (int*)(ws + g1Off);
    int* gcur2     = (int*)(ws + g2Off);

    count_kernel<<<CNT_BLOCKS, 256, 0, stream>>>(rows, partial, E, rpb, rps);
    reduce_kernel<<<NBIN / 256, 256, 0, stream>>>(partial, bincnt);
    scan_kernel<<<1, 256, 0, stream>>>(bincnt, bin_start, gcur1, gcur2,
                                       row_start, N, E);
    pass1_kernel<<<(E + P1_CHUNK - 1) / P1_CHUNK, 256, 0, stream>>>(
        rows, cols, gcur1, tmp, E, rpb);
    pass2_kernel<<<NB * P2_BPB, 256, 0, stream>>>(bin_start, tmp, gcur2, tmp2,
                                                  rps);
    pass3_kernel<<<NBIN, 256, 0, stream>>>(bin_start, tmp2, row_start, dst,
                                           N, rpb, rps);
    // tmp/tmp2/partial dead from here; gemm reuses the slot for h.
    gemm_h_kernel<<<(N + 15) / 16, 256, 0, stream>>>(x, Ww, Wb, h, 0, N);
    long long gthreads = (long long)N * 64;
    gather_kernel<<<(int)((gthreads + 255) / 256), 256, 0, stream>>>(
        row_start, dst, h, out, N);
    return;
  }

  // --- fallback: chunked atomic path (proven, ~1.4 ms) ---
  hipMemsetAsync(d_out, 0, (size_t)out_size * sizeof(float), stream);

  int chunkN = (int)((ws_size / (F_OUT * sizeof(float))) & ~(size_t)15);
  if (chunkN > N) chunkN = N;

  if (chunkN >= 16) {
    float* h = (float*)d_ws;
    int scatterBlocks = (int)(((long long)E * 16 + 255) / 256);
    for (int lo = 0; lo < N; lo += chunkN) {
      int cnt2 = (N - lo < chunkN) ? (N - lo) : chunkN;
      gemm_h_kernel<<<(cnt2 + 15) / 16, 256, 0, stream>>>(x, Ww, Wb, h, lo, cnt2);
      scatter_kernel<<<scatterBlocks, 256, 0, stream>>>(rows, cols, h, out, E,
                                                        lo, lo + cnt2);
    }
  } else {
    long long threads = (long long)E * 64;
    int blocks = (int)((threads + 255) / 256);
    fused_kernel<<<blocks, 256, 0, stream>>>(x, Ww, Wb, rows, cols, out, E);
  }
}